// Round 13
// baseline (9344.225 us; speedup 1.0000x reference)
//
#include <hip/hip_runtime.h>
#include <hip/hip_bf16.h>

// VRAE forward on gfx950. FP32 I/O; MFMA via bf16 hi/lo planes (~fp32 accuracy).
// R20 = R19 (session best config, reproduced twice: 9322.7/9315.1us) minus the
// 128MB workspace memsetAsync (~25-40us of HBM writes in the timed path).
// Correctness without the memset, traced per consumer:
//  - seqA/seqB junk positions [len,512) are never read at consumed indices
//    (stage/prologue clamp tb to [0,len-1]; forward over-reads land only in
//    MFMA output rows discarded by the t<lenRow select; fin_ guards kept path)
//  - hF/hB/hInit and the P weight region are fully written before first read.
// Config: R12 structure (48-frag "+v" pin set, LDS-staged hi planes, XOR
// swizzles, 3-phase step) + LGKM-only barriers + setprio on dec P2/ghpre.
// Perturbation record: residency up/down, transients up, +8 regs all regress;
// scheduler-level zero-reg changes are the only wins.

typedef __bf16 bf16;
typedef __bf16 bf16x8 __attribute__((ext_vector_type(8)));
typedef float f32x4 __attribute__((ext_vector_type(4)));

#define MFMA(a,b,c) __builtin_amdgcn_mfma_f32_16x16x32_bf16((a),(b),(c),0,0,0)
#define Z4 (f32x4){0.f,0.f,0.f,0.f}
// Barrier with LDS-only drain: cross-wave hazards in the step loops are LDS.
#define LGKM_BAR() do { asm volatile("s_waitcnt lgkmcnt(0)" ::: "memory"); \
                        __builtin_amdgcn_s_barrier(); } while(0)

__device__ __forceinline__ float sigm_(float x){ return 1.f/(1.f+__expf(-x)); }
__device__ __forceinline__ float tanh_(float x){
  x = fminf(15.f, fmaxf(-15.f, x));
  float e = __expf(2.f*x);
  return (e-1.f)/(e+1.f);
}
__device__ __forceinline__ float fin_(float v){ return (v - v == 0.0f) ? v : 0.0f; }
// anti-remat pins
__device__ __forceinline__ void pinv_(bf16x8 &v){ asm volatile("" : "+v"(v)); }
__device__ __forceinline__ void pina_(bf16x8 &v){ asm volatile("" : "+a"(v)); }

// ---------------------------------------------------------------------------
// Weight prep: fp32 -> bf16 hi/lo planes in ws.
// ---------------------------------------------------------------------------
struct PrepJobs {
  const float* src[9];
  bf16* hi[9];
  bf16* lo[9];
  int n[9];
};

__global__ void prep_w(PrepJobs J){
  const int stride = gridDim.x*blockDim.x;
  const int t0 = blockIdx.x*blockDim.x + threadIdx.x;
  for (int j=0;j<9;++j){
    const float* __restrict__ s = J.src[j];
    bf16* __restrict__ h = J.hi[j];
    bf16* __restrict__ l = J.lo[j];
    const int n = J.n[j];
    for (int i=t0;i<n;i+=stride){
      float v = fin_(s[i]);
      bf16 hh = (bf16)v;
      h[i] = hh;
      l[i] = (bf16)(v - (float)hh);
    }
  }
}

// ---------------------------------------------------------------------------
// Encoder recurrent kernel (R12, frozen). grid=32. block=512 (8 waves).
// Whh hi/lo resident in ACCUM regs. h double-buffered -> 1 barrier/step.
// ---------------------------------------------------------------------------
template<int KIN, bool F32IN>
__global__ __launch_bounds__(512)
__attribute__((amdgpu_waves_per_eu(2, 2)))
void enc_rec(const void* __restrict__ seqIn_,  // [256,512,KIN] fp32|bf16
             bf16* __restrict__ seqOut,        // [256,512,256] or null
             const bf16* __restrict__ WihHi_, const bf16* __restrict__ WihLo_, // [2,384,KIN]
             const bf16* __restrict__ WhhHi_, const bf16* __restrict__ WhhLo_, // [2,384,128]
             const float* __restrict__ bih_, const float* __restrict__ bhh_,   // [2,384]
             const int* __restrict__ lengths,
             float* __restrict__ hFo, float* __restrict__ hBo)                 // [256,128] or null
{
  constexpr int NKS  = KIN/32;
  constexpr int XSTR = F32IN ? 40 : 264;
  constexpr int XPL  = 16*XSTR;
  constexpr int XSLOT= (F32IN?2:1)*XPL;
  const int tid = threadIdx.x;
  const int wave = tid>>6;
  const int lh   = tid&15;
  const int quad = (tid>>4)&3;
  const int dir  = blockIdx.x>>4;
  const int b0   = (blockIdx.x&15)*16;

  const bf16* __restrict__ WihHi = WihHi_ + (size_t)dir*384*KIN;
  const bf16* __restrict__ WihLo = WihLo_ + (size_t)dir*384*KIN;
  const bf16* __restrict__ WhhHi = WhhHi_ + (size_t)dir*384*128;
  const bf16* __restrict__ WhhLo = WhhLo_ + (size_t)dir*384*128;
  const float* __restrict__ bih = bih_ + dir*384;
  const float* __restrict__ bhh = bhh_ + dir*384;

  __shared__ bf16 hHi[2][16*136], hLo[2][16*136];   // double-buffered: h(t) in buf[t&1]
  __shared__ bf16 xb[4*XSLOT];

  const int jc = wave*16 + lh;
  const int cR = jc, cZ = 128+jc, cN = 256+jc;

  // resident Whh hi/lo frags (24 frags = 96 regs) — pinned into ACCUM segment
  bf16x8 wRH[4],wRL[4],wZH[4],wZL[4],wNH[4],wNL[4];
#pragma unroll
  for (int ks=0;ks<4;++ks){
    const int o = ks*32 + quad*8;
    wRH[ks]=*(const bf16x8*)(WhhHi+(size_t)cR*128+o); wRL[ks]=*(const bf16x8*)(WhhLo+(size_t)cR*128+o);
    wZH[ks]=*(const bf16x8*)(WhhHi+(size_t)cZ*128+o); wZL[ks]=*(const bf16x8*)(WhhLo+(size_t)cZ*128+o);
    wNH[ks]=*(const bf16x8*)(WhhHi+(size_t)cN*128+o); wNL[ks]=*(const bf16x8*)(WhhLo+(size_t)cN*128+o);
    pina_(wRH[ks]); pina_(wRL[ks]); pina_(wZH[ks]); pina_(wZL[ks]); pina_(wNH[ks]); pina_(wNL[ks]);
  }
  const float bR  = bih[cR]+bhh[cR];
  const float bZc = bih[cZ]+bhh[cZ];
  const float bNi = bih[cN];
  const float bNh = bhh[cN];

  int lenRow[4];
#pragma unroll
  for (int r=0;r<4;++r) lenRow[r] = lengths[b0 + quad*4 + r];
  const int lenA = lengths[b0+lh];
  const int Tmax = lengths[b0];
  const int TT   = (Tmax+3)&~3;

  const int wrow = (tid>>4)&15;
  const int wcol = (tid&15)*8;
  const int lenW = lengths[b0 + wrow];
  const int srow = tid>>5;
  const int scol = tid&31;
  const int lenS = lengths[b0 + srow];

  for (int i=tid;i<2*16*136;i+=512){ hHi[0][i]=(bf16)0.f; hLo[0][i]=(bf16)0.f; }

  // thread-local carried state: h(m=quad*4+r, col jc), exact fp32
  float hown[4] = {0.f,0.f,0.f,0.f};

  auto stage = [&](int slot, int sabs){
    int tb = dir ? (lenS-1-sabs) : sabs;
    tb = tb<0 ? 0 : (tb>511 ? 511 : tb);
    if constexpr (F32IN){
      float v = ((const float*)seqIn_)[((size_t)(b0+srow)*512+tb)*32 + scol];
      bf16 hh=(bf16)v;
      xb[slot*XSLOT + srow*XSTR + scol] = hh;
      xb[slot*XSLOT + XPL + srow*XSTR + scol] = (bf16)(v-(float)hh);
    } else {
      bf16x8 v = *(const bf16x8*)((const bf16*)seqIn_ + ((size_t)(b0+srow)*512+tb)*256 + scol*8);
      *(bf16x8*)&xb[slot*XSLOT + srow*XSTR + scol*8] = v;
    }
  };
#pragma unroll
  for (int s=0;s<4;++s) stage(s, 1+s);

  f32x4 accR[4], accZ[4], giN[4];
#pragma unroll
  for (int s=0;s<4;++s){ accR[s]=Z4; accZ[s]=Z4; giN[s]=Z4; }

  // prologue: gi(0) -> slot 3
  {
    int tb0 = dir ? (lenA-1) : 0; tb0 = tb0<0?0:tb0;
#pragma unroll
    for (int ks=0;ks<NKS;++ks){
      const int o = ks*32 + quad*8;
      bf16x8 axH, axL;
      if constexpr (F32IN){
        const float* ap = (const float*)seqIn_ + ((size_t)(b0+lh)*512+tb0)*KIN + o;
#pragma unroll
        for (int e=0;e<8;++e){ float v=ap[e]; bf16 hh=(bf16)v; axH[e]=hh; axL[e]=(bf16)(v-(float)hh); }
      } else {
        axH = *(const bf16x8*)((const bf16*)seqIn_ + ((size_t)(b0+lh)*512+tb0)*KIN + o);
      }
      bf16x8 bH, bL;
      bH=*(const bf16x8*)(WihHi+(size_t)cR*KIN+o); bL=*(const bf16x8*)(WihLo+(size_t)cR*KIN+o);
      accR[3]=MFMA(axH,bH,accR[3]); if constexpr(F32IN) accR[3]=MFMA(axL,bH,accR[3]); accR[3]=MFMA(axH,bL,accR[3]);
      bH=*(const bf16x8*)(WihHi+(size_t)cZ*KIN+o); bL=*(const bf16x8*)(WihLo+(size_t)cZ*KIN+o);
      accZ[3]=MFMA(axH,bH,accZ[3]); if constexpr(F32IN) accZ[3]=MFMA(axL,bH,accZ[3]); accZ[3]=MFMA(axH,bL,accZ[3]);
      bH=*(const bf16x8*)(WihHi+(size_t)cN*KIN+o); bL=*(const bf16x8*)(WihLo+(size_t)cN*KIN+o);
      giN[3]=MFMA(axH,bH,giN[3]);  if constexpr(F32IN) giN[3]=MFMA(axL,bH,giN[3]);  giN[3]=MFMA(axH,bL,giN[3]);
    }
  }
  __syncthreads();

  for (int t4=0; t4<TT; t4+=4){
#pragma unroll
    for (int p=0;p<4;++p){
      const int t = t4 + p;
      const int s = (p+3)&3;
      const int rp = (p+1)&1;   // buffer holding h(t-1)
      const int wp = p&1;       // buffer receiving h(t)
      if (seqOut && tid<256 && t>0 && (t-1)<lenW){
        const int tp = t-1;
        const int tb = dir ? (lenW-1-tp) : tp;
        bf16x8 v = *(const bf16x8*)&hHi[rp][wrow*136 + wcol];
        *(bf16x8*)(seqOut + ((size_t)(b0+wrow)*512 + tb)*256 + dir*128 + wcol) = v;
      }
      f32x4 gN = Z4;
#pragma unroll
      for (int ks=0;ks<4;++ks){
        bf16x8 aH = *(const bf16x8*)&hHi[rp][lh*136 + ks*32 + quad*8];
        bf16x8 aL = *(const bf16x8*)&hLo[rp][lh*136 + ks*32 + quad*8];
        accR[s]=MFMA(aH,wRH[ks],accR[s]); accR[s]=MFMA(aL,wRH[ks],accR[s]); accR[s]=MFMA(aH,wRL[ks],accR[s]);
        accZ[s]=MFMA(aH,wZH[ks],accZ[s]); accZ[s]=MFMA(aL,wZH[ks],accZ[s]); accZ[s]=MFMA(aH,wZL[ks],accZ[s]);
        gN     =MFMA(aH,wNH[ks],gN);      gN     =MFMA(aL,wNH[ks],gN);      gN     =MFMA(aH,wNL[ks],gN);
      }
      float hsel[4];
#pragma unroll
      for (int r=0;r<4;++r){
        float rr = sigm_(accR[s][r] + bR);
        float zz = sigm_(accZ[s][r] + bZc);
        float nn = tanh_(giN[s][r] + bNi + rr*(gN[r] + bNh));
        float hold = hown[r];
        float hnew = fin_((1.f-zz)*nn + zz*hold);
        hsel[r] = (t < lenRow[r]) ? hnew : hold;
        hown[r] = hsel[r];
      }
      if (p==0){
#pragma unroll
        for (int s2=0;s2<4;++s2){ accR[s2]=Z4; accZ[s2]=Z4; giN[s2]=Z4; }
#pragma unroll
        for (int ks=0;ks<NKS;++ks){
          const int o = ks*32 + quad*8;
          bf16x8 axH[4], axL[F32IN?4:1];
#pragma unroll
          for (int s2=0;s2<4;++s2){
            axH[s2] = *(const bf16x8*)&xb[s2*XSLOT + lh*XSTR + o];
            if constexpr (F32IN) axL[s2] = *(const bf16x8*)&xb[s2*XSLOT + XPL + lh*XSTR + o];
          }
          bf16x8 bH, bL;
          bH=*(const bf16x8*)(WihHi+(size_t)cR*KIN+o); bL=*(const bf16x8*)(WihLo+(size_t)cR*KIN+o);
#pragma unroll
          for (int s2=0;s2<4;++s2){
            accR[s2]=MFMA(axH[s2],bH,accR[s2]);
            if constexpr(F32IN) accR[s2]=MFMA(axL[s2],bH,accR[s2]);
            accR[s2]=MFMA(axH[s2],bL,accR[s2]);
          }
          bH=*(const bf16x8*)(WihHi+(size_t)cZ*KIN+o); bL=*(const bf16x8*)(WihLo+(size_t)cZ*KIN+o);
#pragma unroll
          for (int s2=0;s2<4;++s2){
            accZ[s2]=MFMA(axH[s2],bH,accZ[s2]);
            if constexpr(F32IN) accZ[s2]=MFMA(axL[s2],bH,accZ[s2]);
            accZ[s2]=MFMA(axH[s2],bL,accZ[s2]);
          }
          bH=*(const bf16x8*)(WihHi+(size_t)cN*KIN+o); bL=*(const bf16x8*)(WihLo+(size_t)cN*KIN+o);
#pragma unroll
          for (int s2=0;s2<4;++s2){
            giN[s2]=MFMA(axH[s2],bH,giN[s2]);
            if constexpr(F32IN) giN[s2]=MFMA(axL[s2],bH,giN[s2]);
            giN[s2]=MFMA(axH[s2],bL,giN[s2]);
          }
        }
      }
      // write h(t) into the opposite buffer — no WAR vs this step's reads
#pragma unroll
      for (int r=0;r<4;++r){
        const int m = quad*4 + r;
        bf16 hi = (bf16)hsel[r];
        hHi[wp][m*136+jc] = hi;
        hLo[wp][m*136+jc] = (bf16)(hsel[r]-(float)hi);
      }
      if      (p==1){ stage(0, t4+5); stage(1, t4+6); }
      else if (p==2){ stage(2, t4+7); }
      else if (p==3){ stage(3, t4+8); }
      LGKM_BAR();          // LDS-only drain: h(t) + staged x visible
    }
  }
  // last written parity: (TT-1)&1 == 1 (TT is a multiple of 4)
  if (seqOut && tid<256 && (TT-1)<lenW){
    const int tb = dir ? (lenW-1-(TT-1)) : (TT-1);
    bf16x8 v = *(const bf16x8*)&hHi[1][wrow*136 + wcol];
    *(bf16x8*)(seqOut + ((size_t)(b0+wrow)*512 + tb)*256 + dir*128 + wcol) = v;
  }
  float* hout = dir ? hBo : hFo;
  if (hout && tid<256){
#pragma unroll
    for (int e=0;e<8;++e){
      const int j = wcol+e;
      hout[(size_t)(b0+wrow)*128 + j] = fin_((float)hHi[1][wrow*136+j] + (float)hLo[1][wrow*136+j]);
    }
  }
}

// ---------------------------------------------------------------------------
// Latent: mean/logvar/z/h_init. grid=256, block=64. fp32.
// ---------------------------------------------------------------------------
__global__ void latent_k(const float* __restrict__ hF, const float* __restrict__ hB,
                         const float* __restrict__ eps,
                         const float* __restrict__ Wm, const float* __restrict__ bm,
                         const float* __restrict__ Wl, const float* __restrict__ bl,
                         const float* __restrict__ Wz, const float* __restrict__ bz,
                         float* __restrict__ out_mean, float* __restrict__ out_logvar,
                         float* __restrict__ hInit)
{
  const int b = blockIdx.x, tid = threadIdx.x;
  __shared__ float hc[256];
  __shared__ float mv[64];
  __shared__ float zz[32];
  for (int k=tid;k<256;k+=64) hc[k] = fin_((k<128)? hF[(size_t)b*128+k] : hB[(size_t)b*128+k-128]);
  __syncthreads();
  {
    const int i = tid & 31;
    const float* W = (tid<32)? Wm : Wl;
    float acc = (tid<32)? bm[i] : bl[i];
    for (int k=0;k<256;++k) acc += hc[k]*W[i*256+k];
    acc = fin_(acc);
    mv[tid] = acc;
    if (tid<32) out_mean[b*32+i] = acc;
    else        out_logvar[b*32+(tid-32)] = acc;
  }
  __syncthreads();
  if (tid<32) zz[tid] = fin_(mv[tid] + __expf(0.5f*mv[32+tid]) * eps[b*32+tid]);
  __syncthreads();
  for (int j=tid;j<128;j+=64){
    float a = bz[j];
    for (int k=0;k<32;++k) a += zz[k]*Wz[j*32+k];
    hInit[(size_t)b*128 + j] = tanh_(fin_(a));
  }
}

// ---------------------------------------------------------------------------
// Decoder: R12 structure (best measured) + T5 setprio around MFMA clusters
// (P2 + ghpre). grid=16, block=512. W0h+W1h pinned "+v"; W1i-hi, Wo hi/lo,
// W0i-hi in LDS (XOR-swizzled); W0i-lo + W1i-lo stream from L2.
// 3 LGKM barriers/step; gh(t+1) precomputed in P3.
// LDS: h(17,408) + p(2,560) + w1i(98,304) + wo(16,384) + w0i(24,576) = 159,232B
// ---------------------------------------------------------------------------
__global__ __launch_bounds__(512)
__attribute__((amdgpu_waves_per_eu(2, 2)))
void dec_rec(const float* __restrict__ hInit,
             const bf16* __restrict__ W0iH, const bf16* __restrict__ W0iL,  // [384,32]
             const bf16* __restrict__ W0hH, const bf16* __restrict__ W0hL,  // [384,128]
             const bf16* __restrict__ W1iH, const bf16* __restrict__ W1iL,  // [384,128]
             const bf16* __restrict__ W1hH, const bf16* __restrict__ W1hL,  // [384,128]
             const bf16* __restrict__ WoH,  const bf16* __restrict__ WoL,   // [32,128]
             const float* __restrict__ bih0, const float* __restrict__ bhh0,
             const float* __restrict__ bih1, const float* __restrict__ bhh1,
             const float* __restrict__ bout,
             float* __restrict__ rec)        // [256,512,32]
{
  const int tid = threadIdx.x;
  const int wave = tid>>6;
  const int lh   = tid&15;
  const int quad = (tid>>4)&3;
  const int b0 = blockIdx.x*16;
  const int jc = wave*16 + lh;
  const int cR = jc, cZ = 128+jc, cN = 256+jc;

  __shared__ bf16 h1H[16*136], h1L[16*136], h2H[16*136], h2L[16*136];
  __shared__ bf16 pH[16*40], pL[16*40];
  __shared__ bf16 w1iLds[384*128];   // W1i-hi, stride 128, XOR swizzle (row&7)<<3
  __shared__ bf16 woHl[32*128], woLl[32*128];  // Wo hi/lo, XOR swizzle (row&7)<<3
  __shared__ bf16 w0iLds[384*32];    // W0i-hi, stride 32, XOR swizzle (row&3)<<3

  const int sw1 = (jc&7)<<3;   // w1iLds read swizzle
  const int sw0 = (jc&3)<<3;   // w0iLds read swizzle
  const int swo = (lh&7)<<3;   // wo read swizzle (row = wave*16+lh, wave<2)

  // resident W0h, W1h hi/lo (48 frags = 192 regs) — pinned "+v" (R9/R12 config)
  bf16x8 a0RH[4],a0RL[4],a0ZH[4],a0ZL[4],a0NH[4],a0NL[4];
  bf16x8 a1RH[4],a1RL[4],a1ZH[4],a1ZL[4],a1NH[4],a1NL[4];
#pragma unroll
  for (int ks=0;ks<4;++ks){
    const int o = ks*32 + quad*8;
    a0RH[ks]=*(const bf16x8*)(W0hH+(size_t)cR*128+o); a0RL[ks]=*(const bf16x8*)(W0hL+(size_t)cR*128+o);
    a0ZH[ks]=*(const bf16x8*)(W0hH+(size_t)cZ*128+o); a0ZL[ks]=*(const bf16x8*)(W0hL+(size_t)cZ*128+o);
    a0NH[ks]=*(const bf16x8*)(W0hH+(size_t)cN*128+o); a0NL[ks]=*(const bf16x8*)(W0hL+(size_t)cN*128+o);
    a1RH[ks]=*(const bf16x8*)(W1hH+(size_t)cR*128+o); a1RL[ks]=*(const bf16x8*)(W1hL+(size_t)cR*128+o);
    a1ZH[ks]=*(const bf16x8*)(W1hH+(size_t)cZ*128+o); a1ZL[ks]=*(const bf16x8*)(W1hL+(size_t)cZ*128+o);
    a1NH[ks]=*(const bf16x8*)(W1hH+(size_t)cN*128+o); a1NL[ks]=*(const bf16x8*)(W1hL+(size_t)cN*128+o);
    pinv_(a0RH[ks]); pinv_(a0RL[ks]); pinv_(a0ZH[ks]); pinv_(a0ZL[ks]); pinv_(a0NH[ks]); pinv_(a0NL[ks]);
    pinv_(a1RH[ks]); pinv_(a1RL[ks]); pinv_(a1ZH[ks]); pinv_(a1ZL[ks]); pinv_(a1NH[ks]); pinv_(a1NL[ks]);
  }
  const float b1R = bih0[cR]+bhh0[cR], b1Z = bih0[cZ]+bhh0[cZ], b1Ni = bih0[cN], b1Nh = bhh0[cN];
  const float b2R = bih1[cR]+bhh1[cR], b2Z = bih1[cZ]+bhh1[cZ], b2Ni = bih1[cN], b2Nh = bhh1[cN];
  const float bo = (wave<2) ? bout[wave*16+lh] : 0.f;

  // stage W1i-hi into LDS (once), XOR-swizzled stride-128
  for (int i=tid; i<384*16; i+=512){
    const int rr = i>>4, k8 = (i&15)*8;
    *(bf16x8*)&w1iLds[rr*128 + (k8 ^ ((rr&7)<<3))] = *(const bf16x8*)(W1iH + (size_t)rr*128 + k8);
  }
  // stage Wo hi/lo into LDS (once)
  for (int i=tid; i<32*16; i+=512){
    const int rr = i>>4, k8 = (i&15)*8;
    const int c = rr*128 + (k8 ^ ((rr&7)<<3));
    *(bf16x8*)&woHl[c] = *(const bf16x8*)(WoH + (size_t)rr*128 + k8);
    *(bf16x8*)&woLl[c] = *(const bf16x8*)(WoL + (size_t)rr*128 + k8);
  }
  // stage W0i-hi into LDS (once)
  for (int i=tid; i<384*4; i+=512){
    const int rr = i>>2, k8 = (i&3)*8;
    *(bf16x8*)&w0iLds[rr*32 + (k8 ^ ((rr&3)<<3))] = *(const bf16x8*)(W0iH + (size_t)rr*32 + k8);
  }
  // init h1,h2 from hInit; pred = 0
  if (tid < 256){
    const int row = (tid>>4)&15;
    const int c0  = (tid&15)*8;
#pragma unroll
    for (int e=0;e<8;++e){
      const int j = c0+e;
      float v = fin_(hInit[(size_t)(b0+row)*128 + j]);
      bf16 hi=(bf16)v, lo=(bf16)(v-(float)hi);
      h1H[row*136+j]=hi; h1L[row*136+j]=lo;
      h2H[row*136+j]=hi; h2L[row*136+j]=lo;
    }
  }
  for (int i=tid;i<16*40;i+=512){ pH[i]=(bf16)0.f; pL[i]=(bf16)0.f; }
  __syncthreads();

  // persistent gate accumulators (gh precomputed, gi appended)
  f32x4 c1R, c1Z, c1Nh, c2R, c2Z, c2Nh;

  auto ghpre = [&](){
    __builtin_amdgcn_s_setprio(1);
    c1R=Z4; c1Z=Z4; c1Nh=Z4; c2R=Z4; c2Z=Z4; c2Nh=Z4;
#pragma unroll
    for (int ks=0;ks<4;++ks){
      const int o = ks*32 + quad*8;
      bf16x8 aH = *(const bf16x8*)&h1H[lh*136 + o];
      bf16x8 aL = *(const bf16x8*)&h1L[lh*136 + o];
      c1R =MFMA(aH,a0RH[ks],c1R);  c1R =MFMA(aL,a0RH[ks],c1R);  c1R =MFMA(aH,a0RL[ks],c1R);
      c1Z =MFMA(aH,a0ZH[ks],c1Z);  c1Z =MFMA(aL,a0ZH[ks],c1Z);  c1Z =MFMA(aH,a0ZL[ks],c1Z);
      c1Nh=MFMA(aH,a0NH[ks],c1Nh); c1Nh=MFMA(aL,a0NH[ks],c1Nh); c1Nh=MFMA(aH,a0NL[ks],c1Nh);
    }
#pragma unroll
    for (int ks=0;ks<4;++ks){
      const int o = ks*32 + quad*8;
      bf16x8 aH = *(const bf16x8*)&h2H[lh*136 + o];
      bf16x8 aL = *(const bf16x8*)&h2L[lh*136 + o];
      c2R =MFMA(aH,a1RH[ks],c2R);  c2R =MFMA(aL,a1RH[ks],c2R);  c2R =MFMA(aH,a1RL[ks],c2R);
      c2Z =MFMA(aH,a1ZH[ks],c2Z);  c2Z =MFMA(aL,a1ZH[ks],c2Z);  c2Z =MFMA(aH,a1ZL[ks],c2Z);
      c2Nh=MFMA(aH,a1NH[ks],c2Nh); c2Nh=MFMA(aL,a1NH[ks],c2Nh); c2Nh=MFMA(aH,a1NL[ks],c2Nh);
    }
    __builtin_amdgcn_s_setprio(0);
  };
  ghpre();   // gh for t=0 (reads initial h1,h2; post-barrier)

  for (int t=0;t<512;++t){
    // ---- P1: gi1 (pred, K=32; W0i-hi from LDS, lo from L2) + gates1 + write h1(t). ----
    {
      f32x4 c1Ni = Z4;
      bf16x8 aP0 = *(const bf16x8*)&pH[lh*40 + quad*8];
      bf16x8 aP1 = *(const bf16x8*)&pL[lh*40 + quad*8];
      const int o = quad*8;
      bf16x8 bH,bL;
      bH=*(const bf16x8*)&w0iLds[cR*32 + (o^sw0)]; bL=*(const bf16x8*)(W0iL+(size_t)cR*32+o);
      c1R=MFMA(aP0,bH,c1R); c1R=MFMA(aP1,bH,c1R); c1R=MFMA(aP0,bL,c1R);
      bH=*(const bf16x8*)&w0iLds[cZ*32 + (o^sw0)]; bL=*(const bf16x8*)(W0iL+(size_t)cZ*32+o);
      c1Z=MFMA(aP0,bH,c1Z); c1Z=MFMA(aP1,bH,c1Z); c1Z=MFMA(aP0,bL,c1Z);
      bH=*(const bf16x8*)&w0iLds[cN*32 + (o^sw0)]; bL=*(const bf16x8*)(W0iL+(size_t)cN*32+o);
      c1Ni=MFMA(aP0,bH,c1Ni); c1Ni=MFMA(aP1,bH,c1Ni); c1Ni=MFMA(aP0,bL,c1Ni);
#pragma unroll
      for (int r=0;r<4;++r){
        const int m = quad*4+r;
        float rr = sigm_(c1R[r] + b1R);
        float z  = sigm_(c1Z[r] + b1Z);
        float nn = tanh_(c1Ni[r] + b1Ni + rr*(c1Nh[r] + b1Nh));
        float hold = (float)h1H[m*136+jc] + (float)h1L[m*136+jc];
        float hnew = fin_((1.f-z)*nn + z*hold);
        bf16 hi=(bf16)hnew;
        h1H[m*136+jc]=hi; h1L[m*136+jc]=(bf16)(hnew-(float)hi);
      }
    }
    LGKM_BAR();                            // B1: h1(t) visible (LDS drain only)
    // ---- P2: gi2 (h1(t), K=128; W1i-hi from LDS, lo from L2) + gates2 + write h2(t) ----
    {
      f32x4 c2Ni = Z4;
      __builtin_amdgcn_s_setprio(1);
#pragma unroll
      for (int ks=0;ks<4;++ks){
        const int o = ks*32 + quad*8;
        bf16x8 aH = *(const bf16x8*)&h1H[lh*136 + o];
        bf16x8 aL = *(const bf16x8*)&h1L[lh*136 + o];
        bf16x8 bH,bL;
        bH=*(const bf16x8*)&w1iLds[cR*128+(o^sw1)]; bL=*(const bf16x8*)(W1iL+(size_t)cR*128+o);
        c2R=MFMA(aH,bH,c2R); c2R=MFMA(aL,bH,c2R); c2R=MFMA(aH,bL,c2R);
        bH=*(const bf16x8*)&w1iLds[cZ*128+(o^sw1)]; bL=*(const bf16x8*)(W1iL+(size_t)cZ*128+o);
        c2Z=MFMA(aH,bH,c2Z); c2Z=MFMA(aL,bH,c2Z); c2Z=MFMA(aH,bL,c2Z);
        bH=*(const bf16x8*)&w1iLds[cN*128+(o^sw1)]; bL=*(const bf16x8*)(W1iL+(size_t)cN*128+o);
        c2Ni=MFMA(aH,bH,c2Ni); c2Ni=MFMA(aL,bH,c2Ni); c2Ni=MFMA(aH,bL,c2Ni);
      }
      __builtin_amdgcn_s_setprio(0);
#pragma unroll
      for (int r=0;r<4;++r){
        const int m = quad*4+r;
        float rr = sigm_(c2R[r] + b2R);
        float z  = sigm_(c2Z[r] + b2Z);
        float nn = tanh_(c2Ni[r] + b2Ni + rr*(c2Nh[r] + b2Nh));
        float hold = (float)h2H[m*136+jc] + (float)h2L[m*136+jc];
        float hnew = fin_((1.f-z)*nn + z*hold);
        bf16 hi=(bf16)hnew;
        h2H[m*136+jc]=hi; h2L[m*136+jc]=(bf16)(hnew-(float)hi);
      }
    }
    LGKM_BAR();                            // B2: h2(t) visible (LDS drain only)
    // ---- P3: out-proj (waves 0,1; Wo from LDS) + gh precompute for t+1 (all waves) ----
    if (wave<2){
      f32x4 po=Z4;
#pragma unroll
      for (int ks=0;ks<4;++ks){
        const int o = ks*32 + quad*8;
        bf16x8 oH = *(const bf16x8*)&h2H[lh*136 + o];
        bf16x8 oL = *(const bf16x8*)&h2L[lh*136 + o];
        const int wc = (wave*16+lh)*128 + (o^swo);
        bf16x8 bH = *(const bf16x8*)&woHl[wc];
        bf16x8 bL = *(const bf16x8*)&woLl[wc];
        po=MFMA(oH,bH,po); po=MFMA(oL,bH,po); po=MFMA(oH,bL,po);
      }
#pragma unroll
      for (int r=0;r<4;++r){
        const int m = quad*4+r;
        float pv = fin_(po[r]+bo);
        rec[((size_t)(b0+m)*512 + t)*32 + wave*16+lh] = pv;   // store floats across barrier
        bf16 hi=(bf16)pv;
        pH[m*40 + wave*16+lh]=hi; pL[m*40 + wave*16+lh]=(bf16)(pv-(float)hi);
      }
    }
    if (t+1 < 512) ghpre();                // reads h1(t),h2(t) — post-B2
    LGKM_BAR();                            // B3: pred(t) LDS visible; h reads done
  }
}

// ---------------------------------------------------------------------------
extern "C" void kernel_launch(void* const* d_in, const int* in_sizes, int n_in,
                              void* d_out, int out_size, void* d_ws, size_t ws_size,
                              hipStream_t stream)
{
  const float* x       = (const float*)d_in[0];
  const int*   lengths = (const int*)d_in[1];
  const float* eps     = (const float*)d_in[2];
  const float* eWih0   = (const float*)d_in[3];
  const float* eWhh0   = (const float*)d_in[4];
  const float* ebih0   = (const float*)d_in[5];
  const float* ebhh0   = (const float*)d_in[6];
  const float* eWih12  = (const float*)d_in[7];
  const float* eWhh12  = (const float*)d_in[8];
  const float* ebih12  = (const float*)d_in[9];
  const float* ebhh12  = (const float*)d_in[10];
  const float* dWih0   = (const float*)d_in[11];
  const float* dWhh0   = (const float*)d_in[12];
  const float* dbih0   = (const float*)d_in[13];
  const float* dbhh0   = (const float*)d_in[14];
  const float* dWih1   = (const float*)d_in[15];
  const float* dWhh1   = (const float*)d_in[16];
  const float* dbih1   = (const float*)d_in[17];
  const float* dbhh1   = (const float*)d_in[18];
  const float* Wm      = (const float*)d_in[19];
  const float* bm      = (const float*)d_in[20];
  const float* Wl      = (const float*)d_in[21];
  const float* bl      = (const float*)d_in[22];
  const float* Wz      = (const float*)d_in[23];
  const float* bz      = (const float*)d_in[24];
  const float* Wo      = (const float*)d_in[25];
  const float* bo      = (const float*)d_in[26];

  char* ws = (char*)d_ws;
  bf16* P     = (bf16*)ws;
  bf16* seqA  = (bf16*)(ws + (size_t)(4<<20));
  bf16* seqB  = (bf16*)(ws + (size_t)(68<<20));
  float* hF    = (float*)seqA;
  float* hB    = hF + 256*128;
  float* hInit = hB + 256*128;

  const size_t O_eWih0  = 0;
  const size_t O_eWhh0  = 49152;
  const size_t O_eWih12 = 245760;
  const size_t O_eWhh12 = 1032192;
  const size_t O_dWih0  = 1425408;
  const size_t O_dWhh0  = 1449984;
  const size_t O_dWih1  = 1548288;
  const size_t O_dWhh1  = 1646592;
  const size_t O_Wout   = 1744896;

  float* out   = (float*)d_out;
  float* rec   = out;
  float* omean = out + (size_t)4194304;
  float* ologv = omean + 8192;

  // R20: no workspace memset — kernel output is independent of initial ws
  // contents (unwritten seq positions are never read at consumed indices;
  // all other regions are fully written before first read).

  PrepJobs J;
  const float* srcs[9] = {eWih0, eWhh0, eWih12, eWhh12, dWih0, dWhh0, dWih1, dWhh1, Wo};
  const size_t offs[9] = {O_eWih0,O_eWhh0,O_eWih12,O_eWhh12,O_dWih0,O_dWhh0,O_dWih1,O_dWhh1,O_Wout};
  const int    ns[9]   = {24576, 98304, 393216, 196608, 12288, 49152, 49152, 49152, 4096};
  for (int j=0;j<9;++j){ J.src[j]=srcs[j]; J.hi[j]=P+offs[j]; J.lo[j]=P+offs[j]+ns[j]; J.n[j]=ns[j]; }
  prep_w<<<256, 256, 0, stream>>>(J);

  dim3 blk(512);

  enc_rec<32,true><<<32, blk, 0, stream>>>(x, seqA,
      P+O_eWih0, P+O_eWih0+24576, P+O_eWhh0, P+O_eWhh0+98304,
      ebih0, ebhh0, lengths, nullptr, nullptr);
  enc_rec<256,false><<<32, blk, 0, stream>>>(seqA, seqB,
      P+O_eWih12, P+O_eWih12+393216, P+O_eWhh12, P+O_eWhh12+196608,
      ebih12, ebhh12, lengths, nullptr, nullptr);
  enc_rec<256,false><<<32, blk, 0, stream>>>(seqB, nullptr,
      P+O_eWih12+196608, P+O_eWih12+393216+196608,
      P+O_eWhh12+98304,  P+O_eWhh12+196608+98304,
      ebih12+768, ebhh12+768, lengths, hF, hB);
  latent_k<<<256, 64, 0, stream>>>(hF, hB, eps, Wm, bm, Wl, bl, Wz, bz,
                                   omean, ologv, hInit);
  dec_rec<<<16, blk, 0, stream>>>(hInit,
      P+O_dWih0, P+O_dWih0+12288, P+O_dWhh0, P+O_dWhh0+49152,
      P+O_dWih1, P+O_dWih1+49152, P+O_dWhh1, P+O_dWhh1+49152,
      P+O_Wout,  P+O_Wout+4096,
      dbih0, dbhh0, dbih1, dbhh1, bo, rec);
}

// Round 14
// 9299.950 us; speedup vs baseline: 1.0048x; 1.0048x over previous
//
#include <hip/hip_runtime.h>
#include <hip/hip_bf16.h>

// VRAE forward on gfx950. FP32 I/O; MFMA via bf16 hi/lo planes (~fp32 accuracy).
// R21 = R20 byte-identical — FINAL LOCK-IN of the session-best configuration.
// Config: R12 structure (48-frag "+v" pin set, LDS-staged hi planes, XOR
// swizzles, 3-phase dec step) + LGKM-only barriers + setprio on dec P2/ghpre
// + no workspace memset. Three reproductions: 9322.7 / 9315.1 / 9344.2 us
// (noise +-0.3%). Session ledger: 11 configs measured; all structural
// perturbations (residency up/down, transients up, +8 regs, asm-MFMA)
// regressed proportionally to register-demand delta; only scheduler-level
// zero-cost changes won. Not a HW roofline (MfmaUtil ~1.2%) — a serial-
// recurrence latency floor for this decomposition.

typedef __bf16 bf16;
typedef __bf16 bf16x8 __attribute__((ext_vector_type(8)));
typedef float f32x4 __attribute__((ext_vector_type(4)));

#define MFMA(a,b,c) __builtin_amdgcn_mfma_f32_16x16x32_bf16((a),(b),(c),0,0,0)
#define Z4 (f32x4){0.f,0.f,0.f,0.f}
// Barrier with LDS-only drain: cross-wave hazards in the step loops are LDS.
#define LGKM_BAR() do { asm volatile("s_waitcnt lgkmcnt(0)" ::: "memory"); \
                        __builtin_amdgcn_s_barrier(); } while(0)

__device__ __forceinline__ float sigm_(float x){ return 1.f/(1.f+__expf(-x)); }
__device__ __forceinline__ float tanh_(float x){
  x = fminf(15.f, fmaxf(-15.f, x));
  float e = __expf(2.f*x);
  return (e-1.f)/(e+1.f);
}
__device__ __forceinline__ float fin_(float v){ return (v - v == 0.0f) ? v : 0.0f; }
// anti-remat pins
__device__ __forceinline__ void pinv_(bf16x8 &v){ asm volatile("" : "+v"(v)); }
__device__ __forceinline__ void pina_(bf16x8 &v){ asm volatile("" : "+a"(v)); }

// ---------------------------------------------------------------------------
// Weight prep: fp32 -> bf16 hi/lo planes in ws.
// ---------------------------------------------------------------------------
struct PrepJobs {
  const float* src[9];
  bf16* hi[9];
  bf16* lo[9];
  int n[9];
};

__global__ void prep_w(PrepJobs J){
  const int stride = gridDim.x*blockDim.x;
  const int t0 = blockIdx.x*blockDim.x + threadIdx.x;
  for (int j=0;j<9;++j){
    const float* __restrict__ s = J.src[j];
    bf16* __restrict__ h = J.hi[j];
    bf16* __restrict__ l = J.lo[j];
    const int n = J.n[j];
    for (int i=t0;i<n;i+=stride){
      float v = fin_(s[i]);
      bf16 hh = (bf16)v;
      h[i] = hh;
      l[i] = (bf16)(v - (float)hh);
    }
  }
}

// ---------------------------------------------------------------------------
// Encoder recurrent kernel (R12, frozen). grid=32. block=512 (8 waves).
// Whh hi/lo resident in ACCUM regs. h double-buffered -> 1 barrier/step.
// ---------------------------------------------------------------------------
template<int KIN, bool F32IN>
__global__ __launch_bounds__(512)
__attribute__((amdgpu_waves_per_eu(2, 2)))
void enc_rec(const void* __restrict__ seqIn_,  // [256,512,KIN] fp32|bf16
             bf16* __restrict__ seqOut,        // [256,512,256] or null
             const bf16* __restrict__ WihHi_, const bf16* __restrict__ WihLo_, // [2,384,KIN]
             const bf16* __restrict__ WhhHi_, const bf16* __restrict__ WhhLo_, // [2,384,128]
             const float* __restrict__ bih_, const float* __restrict__ bhh_,   // [2,384]
             const int* __restrict__ lengths,
             float* __restrict__ hFo, float* __restrict__ hBo)                 // [256,128] or null
{
  constexpr int NKS  = KIN/32;
  constexpr int XSTR = F32IN ? 40 : 264;
  constexpr int XPL  = 16*XSTR;
  constexpr int XSLOT= (F32IN?2:1)*XPL;
  const int tid = threadIdx.x;
  const int wave = tid>>6;
  const int lh   = tid&15;
  const int quad = (tid>>4)&3;
  const int dir  = blockIdx.x>>4;
  const int b0   = (blockIdx.x&15)*16;

  const bf16* __restrict__ WihHi = WihHi_ + (size_t)dir*384*KIN;
  const bf16* __restrict__ WihLo = WihLo_ + (size_t)dir*384*KIN;
  const bf16* __restrict__ WhhHi = WhhHi_ + (size_t)dir*384*128;
  const bf16* __restrict__ WhhLo = WhhLo_ + (size_t)dir*384*128;
  const float* __restrict__ bih = bih_ + dir*384;
  const float* __restrict__ bhh = bhh_ + dir*384;

  __shared__ bf16 hHi[2][16*136], hLo[2][16*136];   // double-buffered: h(t) in buf[t&1]
  __shared__ bf16 xb[4*XSLOT];

  const int jc = wave*16 + lh;
  const int cR = jc, cZ = 128+jc, cN = 256+jc;

  // resident Whh hi/lo frags (24 frags = 96 regs) — pinned into ACCUM segment
  bf16x8 wRH[4],wRL[4],wZH[4],wZL[4],wNH[4],wNL[4];
#pragma unroll
  for (int ks=0;ks<4;++ks){
    const int o = ks*32 + quad*8;
    wRH[ks]=*(const bf16x8*)(WhhHi+(size_t)cR*128+o); wRL[ks]=*(const bf16x8*)(WhhLo+(size_t)cR*128+o);
    wZH[ks]=*(const bf16x8*)(WhhHi+(size_t)cZ*128+o); wZL[ks]=*(const bf16x8*)(WhhLo+(size_t)cZ*128+o);
    wNH[ks]=*(const bf16x8*)(WhhHi+(size_t)cN*128+o); wNL[ks]=*(const bf16x8*)(WhhLo+(size_t)cN*128+o);
    pina_(wRH[ks]); pina_(wRL[ks]); pina_(wZH[ks]); pina_(wZL[ks]); pina_(wNH[ks]); pina_(wNL[ks]);
  }
  const float bR  = bih[cR]+bhh[cR];
  const float bZc = bih[cZ]+bhh[cZ];
  const float bNi = bih[cN];
  const float bNh = bhh[cN];

  int lenRow[4];
#pragma unroll
  for (int r=0;r<4;++r) lenRow[r] = lengths[b0 + quad*4 + r];
  const int lenA = lengths[b0+lh];
  const int Tmax = lengths[b0];
  const int TT   = (Tmax+3)&~3;

  const int wrow = (tid>>4)&15;
  const int wcol = (tid&15)*8;
  const int lenW = lengths[b0 + wrow];
  const int srow = tid>>5;
  const int scol = tid&31;
  const int lenS = lengths[b0 + srow];

  for (int i=tid;i<2*16*136;i+=512){ hHi[0][i]=(bf16)0.f; hLo[0][i]=(bf16)0.f; }

  // thread-local carried state: h(m=quad*4+r, col jc), exact fp32
  float hown[4] = {0.f,0.f,0.f,0.f};

  auto stage = [&](int slot, int sabs){
    int tb = dir ? (lenS-1-sabs) : sabs;
    tb = tb<0 ? 0 : (tb>511 ? 511 : tb);
    if constexpr (F32IN){
      float v = ((const float*)seqIn_)[((size_t)(b0+srow)*512+tb)*32 + scol];
      bf16 hh=(bf16)v;
      xb[slot*XSLOT + srow*XSTR + scol] = hh;
      xb[slot*XSLOT + XPL + srow*XSTR + scol] = (bf16)(v-(float)hh);
    } else {
      bf16x8 v = *(const bf16x8*)((const bf16*)seqIn_ + ((size_t)(b0+srow)*512+tb)*256 + scol*8);
      *(bf16x8*)&xb[slot*XSLOT + srow*XSTR + scol*8] = v;
    }
  };
#pragma unroll
  for (int s=0;s<4;++s) stage(s, 1+s);

  f32x4 accR[4], accZ[4], giN[4];
#pragma unroll
  for (int s=0;s<4;++s){ accR[s]=Z4; accZ[s]=Z4; giN[s]=Z4; }

  // prologue: gi(0) -> slot 3
  {
    int tb0 = dir ? (lenA-1) : 0; tb0 = tb0<0?0:tb0;
#pragma unroll
    for (int ks=0;ks<NKS;++ks){
      const int o = ks*32 + quad*8;
      bf16x8 axH, axL;
      if constexpr (F32IN){
        const float* ap = (const float*)seqIn_ + ((size_t)(b0+lh)*512+tb0)*KIN + o;
#pragma unroll
        for (int e=0;e<8;++e){ float v=ap[e]; bf16 hh=(bf16)v; axH[e]=hh; axL[e]=(bf16)(v-(float)hh); }
      } else {
        axH = *(const bf16x8*)((const bf16*)seqIn_ + ((size_t)(b0+lh)*512+tb0)*KIN + o);
      }
      bf16x8 bH, bL;
      bH=*(const bf16x8*)(WihHi+(size_t)cR*KIN+o); bL=*(const bf16x8*)(WihLo+(size_t)cR*KIN+o);
      accR[3]=MFMA(axH,bH,accR[3]); if constexpr(F32IN) accR[3]=MFMA(axL,bH,accR[3]); accR[3]=MFMA(axH,bL,accR[3]);
      bH=*(const bf16x8*)(WihHi+(size_t)cZ*KIN+o); bL=*(const bf16x8*)(WihLo+(size_t)cZ*KIN+o);
      accZ[3]=MFMA(axH,bH,accZ[3]); if constexpr(F32IN) accZ[3]=MFMA(axL,bH,accZ[3]); accZ[3]=MFMA(axH,bL,accZ[3]);
      bH=*(const bf16x8*)(WihHi+(size_t)cN*KIN+o); bL=*(const bf16x8*)(WihLo+(size_t)cN*KIN+o);
      giN[3]=MFMA(axH,bH,giN[3]);  if constexpr(F32IN) giN[3]=MFMA(axL,bH,giN[3]);  giN[3]=MFMA(axH,bL,giN[3]);
    }
  }
  __syncthreads();

  for (int t4=0; t4<TT; t4+=4){
#pragma unroll
    for (int p=0;p<4;++p){
      const int t = t4 + p;
      const int s = (p+3)&3;
      const int rp = (p+1)&1;   // buffer holding h(t-1)
      const int wp = p&1;       // buffer receiving h(t)
      if (seqOut && tid<256 && t>0 && (t-1)<lenW){
        const int tp = t-1;
        const int tb = dir ? (lenW-1-tp) : tp;
        bf16x8 v = *(const bf16x8*)&hHi[rp][wrow*136 + wcol];
        *(bf16x8*)(seqOut + ((size_t)(b0+wrow)*512 + tb)*256 + dir*128 + wcol) = v;
      }
      f32x4 gN = Z4;
#pragma unroll
      for (int ks=0;ks<4;++ks){
        bf16x8 aH = *(const bf16x8*)&hHi[rp][lh*136 + ks*32 + quad*8];
        bf16x8 aL = *(const bf16x8*)&hLo[rp][lh*136 + ks*32 + quad*8];
        accR[s]=MFMA(aH,wRH[ks],accR[s]); accR[s]=MFMA(aL,wRH[ks],accR[s]); accR[s]=MFMA(aH,wRL[ks],accR[s]);
        accZ[s]=MFMA(aH,wZH[ks],accZ[s]); accZ[s]=MFMA(aL,wZH[ks],accZ[s]); accZ[s]=MFMA(aH,wZL[ks],accZ[s]);
        gN     =MFMA(aH,wNH[ks],gN);      gN     =MFMA(aL,wNH[ks],gN);      gN     =MFMA(aH,wNL[ks],gN);
      }
      float hsel[4];
#pragma unroll
      for (int r=0;r<4;++r){
        float rr = sigm_(accR[s][r] + bR);
        float zz = sigm_(accZ[s][r] + bZc);
        float nn = tanh_(giN[s][r] + bNi + rr*(gN[r] + bNh));
        float hold = hown[r];
        float hnew = fin_((1.f-zz)*nn + zz*hold);
        hsel[r] = (t < lenRow[r]) ? hnew : hold;
        hown[r] = hsel[r];
      }
      if (p==0){
#pragma unroll
        for (int s2=0;s2<4;++s2){ accR[s2]=Z4; accZ[s2]=Z4; giN[s2]=Z4; }
#pragma unroll
        for (int ks=0;ks<NKS;++ks){
          const int o = ks*32 + quad*8;
          bf16x8 axH[4], axL[F32IN?4:1];
#pragma unroll
          for (int s2=0;s2<4;++s2){
            axH[s2] = *(const bf16x8*)&xb[s2*XSLOT + lh*XSTR + o];
            if constexpr (F32IN) axL[s2] = *(const bf16x8*)&xb[s2*XSLOT + XPL + lh*XSTR + o];
          }
          bf16x8 bH, bL;
          bH=*(const bf16x8*)(WihHi+(size_t)cR*KIN+o); bL=*(const bf16x8*)(WihLo+(size_t)cR*KIN+o);
#pragma unroll
          for (int s2=0;s2<4;++s2){
            accR[s2]=MFMA(axH[s2],bH,accR[s2]);
            if constexpr(F32IN) accR[s2]=MFMA(axL[s2],bH,accR[s2]);
            accR[s2]=MFMA(axH[s2],bL,accR[s2]);
          }
          bH=*(const bf16x8*)(WihHi+(size_t)cZ*KIN+o); bL=*(const bf16x8*)(WihLo+(size_t)cZ*KIN+o);
#pragma unroll
          for (int s2=0;s2<4;++s2){
            accZ[s2]=MFMA(axH[s2],bH,accZ[s2]);
            if constexpr(F32IN) accZ[s2]=MFMA(axL[s2],bH,accZ[s2]);
            accZ[s2]=MFMA(axH[s2],bL,accZ[s2]);
          }
          bH=*(const bf16x8*)(WihHi+(size_t)cN*KIN+o); bL=*(const bf16x8*)(WihLo+(size_t)cN*KIN+o);
#pragma unroll
          for (int s2=0;s2<4;++s2){
            giN[s2]=MFMA(axH[s2],bH,giN[s2]);
            if constexpr(F32IN) giN[s2]=MFMA(axL[s2],bH,giN[s2]);
            giN[s2]=MFMA(axH[s2],bL,giN[s2]);
          }
        }
      }
      // write h(t) into the opposite buffer — no WAR vs this step's reads
#pragma unroll
      for (int r=0;r<4;++r){
        const int m = quad*4 + r;
        bf16 hi = (bf16)hsel[r];
        hHi[wp][m*136+jc] = hi;
        hLo[wp][m*136+jc] = (bf16)(hsel[r]-(float)hi);
      }
      if      (p==1){ stage(0, t4+5); stage(1, t4+6); }
      else if (p==2){ stage(2, t4+7); }
      else if (p==3){ stage(3, t4+8); }
      LGKM_BAR();          // LDS-only drain: h(t) + staged x visible
    }
  }
  // last written parity: (TT-1)&1 == 1 (TT is a multiple of 4)
  if (seqOut && tid<256 && (TT-1)<lenW){
    const int tb = dir ? (lenW-1-(TT-1)) : (TT-1);
    bf16x8 v = *(const bf16x8*)&hHi[1][wrow*136 + wcol];
    *(bf16x8*)(seqOut + ((size_t)(b0+wrow)*512 + tb)*256 + dir*128 + wcol) = v;
  }
  float* hout = dir ? hBo : hFo;
  if (hout && tid<256){
#pragma unroll
    for (int e=0;e<8;++e){
      const int j = wcol+e;
      hout[(size_t)(b0+wrow)*128 + j] = fin_((float)hHi[1][wrow*136+j] + (float)hLo[1][wrow*136+j]);
    }
  }
}

// ---------------------------------------------------------------------------
// Latent: mean/logvar/z/h_init. grid=256, block=64. fp32.
// ---------------------------------------------------------------------------
__global__ void latent_k(const float* __restrict__ hF, const float* __restrict__ hB,
                         const float* __restrict__ eps,
                         const float* __restrict__ Wm, const float* __restrict__ bm,
                         const float* __restrict__ Wl, const float* __restrict__ bl,
                         const float* __restrict__ Wz, const float* __restrict__ bz,
                         float* __restrict__ out_mean, float* __restrict__ out_logvar,
                         float* __restrict__ hInit)
{
  const int b = blockIdx.x, tid = threadIdx.x;
  __shared__ float hc[256];
  __shared__ float mv[64];
  __shared__ float zz[32];
  for (int k=tid;k<256;k+=64) hc[k] = fin_((k<128)? hF[(size_t)b*128+k] : hB[(size_t)b*128+k-128]);
  __syncthreads();
  {
    const int i = tid & 31;
    const float* W = (tid<32)? Wm : Wl;
    float acc = (tid<32)? bm[i] : bl[i];
    for (int k=0;k<256;++k) acc += hc[k]*W[i*256+k];
    acc = fin_(acc);
    mv[tid] = acc;
    if (tid<32) out_mean[b*32+i] = acc;
    else        out_logvar[b*32+(tid-32)] = acc;
  }
  __syncthreads();
  if (tid<32) zz[tid] = fin_(mv[tid] + __expf(0.5f*mv[32+tid]) * eps[b*32+tid]);
  __syncthreads();
  for (int j=tid;j<128;j+=64){
    float a = bz[j];
    for (int k=0;k<32;++k) a += zz[k]*Wz[j*32+k];
    hInit[(size_t)b*128 + j] = tanh_(fin_(a));
  }
}

// ---------------------------------------------------------------------------
// Decoder: R12 structure (best measured) + T5 setprio around MFMA clusters
// (P2 + ghpre). grid=16, block=512. W0h+W1h pinned "+v"; W1i-hi, Wo hi/lo,
// W0i-hi in LDS (XOR-swizzled); W0i-lo + W1i-lo stream from L2.
// 3 LGKM barriers/step; gh(t+1) precomputed in P3.
// LDS: h(17,408) + p(2,560) + w1i(98,304) + wo(16,384) + w0i(24,576) = 159,232B
// ---------------------------------------------------------------------------
__global__ __launch_bounds__(512)
__attribute__((amdgpu_waves_per_eu(2, 2)))
void dec_rec(const float* __restrict__ hInit,
             const bf16* __restrict__ W0iH, const bf16* __restrict__ W0iL,  // [384,32]
             const bf16* __restrict__ W0hH, const bf16* __restrict__ W0hL,  // [384,128]
             const bf16* __restrict__ W1iH, const bf16* __restrict__ W1iL,  // [384,128]
             const bf16* __restrict__ W1hH, const bf16* __restrict__ W1hL,  // [384,128]
             const bf16* __restrict__ WoH,  const bf16* __restrict__ WoL,   // [32,128]
             const float* __restrict__ bih0, const float* __restrict__ bhh0,
             const float* __restrict__ bih1, const float* __restrict__ bhh1,
             const float* __restrict__ bout,
             float* __restrict__ rec)        // [256,512,32]
{
  const int tid = threadIdx.x;
  const int wave = tid>>6;
  const int lh   = tid&15;
  const int quad = (tid>>4)&3;
  const int b0 = blockIdx.x*16;
  const int jc = wave*16 + lh;
  const int cR = jc, cZ = 128+jc, cN = 256+jc;

  __shared__ bf16 h1H[16*136], h1L[16*136], h2H[16*136], h2L[16*136];
  __shared__ bf16 pH[16*40], pL[16*40];
  __shared__ bf16 w1iLds[384*128];   // W1i-hi, stride 128, XOR swizzle (row&7)<<3
  __shared__ bf16 woHl[32*128], woLl[32*128];  // Wo hi/lo, XOR swizzle (row&7)<<3
  __shared__ bf16 w0iLds[384*32];    // W0i-hi, stride 32, XOR swizzle (row&3)<<3

  const int sw1 = (jc&7)<<3;   // w1iLds read swizzle
  const int sw0 = (jc&3)<<3;   // w0iLds read swizzle
  const int swo = (lh&7)<<3;   // wo read swizzle (row = wave*16+lh, wave<2)

  // resident W0h, W1h hi/lo (48 frags = 192 regs) — pinned "+v" (R9/R12 config)
  bf16x8 a0RH[4],a0RL[4],a0ZH[4],a0ZL[4],a0NH[4],a0NL[4];
  bf16x8 a1RH[4],a1RL[4],a1ZH[4],a1ZL[4],a1NH[4],a1NL[4];
#pragma unroll
  for (int ks=0;ks<4;++ks){
    const int o = ks*32 + quad*8;
    a0RH[ks]=*(const bf16x8*)(W0hH+(size_t)cR*128+o); a0RL[ks]=*(const bf16x8*)(W0hL+(size_t)cR*128+o);
    a0ZH[ks]=*(const bf16x8*)(W0hH+(size_t)cZ*128+o); a0ZL[ks]=*(const bf16x8*)(W0hL+(size_t)cZ*128+o);
    a0NH[ks]=*(const bf16x8*)(W0hH+(size_t)cN*128+o); a0NL[ks]=*(const bf16x8*)(W0hL+(size_t)cN*128+o);
    a1RH[ks]=*(const bf16x8*)(W1hH+(size_t)cR*128+o); a1RL[ks]=*(const bf16x8*)(W1hL+(size_t)cR*128+o);
    a1ZH[ks]=*(const bf16x8*)(W1hH+(size_t)cZ*128+o); a1ZL[ks]=*(const bf16x8*)(W1hL+(size_t)cZ*128+o);
    a1NH[ks]=*(const bf16x8*)(W1hH+(size_t)cN*128+o); a1NL[ks]=*(const bf16x8*)(W1hL+(size_t)cN*128+o);
    pinv_(a0RH[ks]); pinv_(a0RL[ks]); pinv_(a0ZH[ks]); pinv_(a0ZL[ks]); pinv_(a0NH[ks]); pinv_(a0NL[ks]);
    pinv_(a1RH[ks]); pinv_(a1RL[ks]); pinv_(a1ZH[ks]); pinv_(a1ZL[ks]); pinv_(a1NH[ks]); pinv_(a1NL[ks]);
  }
  const float b1R = bih0[cR]+bhh0[cR], b1Z = bih0[cZ]+bhh0[cZ], b1Ni = bih0[cN], b1Nh = bhh0[cN];
  const float b2R = bih1[cR]+bhh1[cR], b2Z = bih1[cZ]+bhh1[cZ], b2Ni = bih1[cN], b2Nh = bhh1[cN];
  const float bo = (wave<2) ? bout[wave*16+lh] : 0.f;

  // stage W1i-hi into LDS (once), XOR-swizzled stride-128
  for (int i=tid; i<384*16; i+=512){
    const int rr = i>>4, k8 = (i&15)*8;
    *(bf16x8*)&w1iLds[rr*128 + (k8 ^ ((rr&7)<<3))] = *(const bf16x8*)(W1iH + (size_t)rr*128 + k8);
  }
  // stage Wo hi/lo into LDS (once)
  for (int i=tid; i<32*16; i+=512){
    const int rr = i>>4, k8 = (i&15)*8;
    const int c = rr*128 + (k8 ^ ((rr&7)<<3));
    *(bf16x8*)&woHl[c] = *(const bf16x8*)(WoH + (size_t)rr*128 + k8);
    *(bf16x8*)&woLl[c] = *(const bf16x8*)(WoL + (size_t)rr*128 + k8);
  }
  // stage W0i-hi into LDS (once)
  for (int i=tid; i<384*4; i+=512){
    const int rr = i>>2, k8 = (i&3)*8;
    *(bf16x8*)&w0iLds[rr*32 + (k8 ^ ((rr&3)<<3))] = *(const bf16x8*)(W0iH + (size_t)rr*32 + k8);
  }
  // init h1,h2 from hInit; pred = 0
  if (tid < 256){
    const int row = (tid>>4)&15;
    const int c0  = (tid&15)*8;
#pragma unroll
    for (int e=0;e<8;++e){
      const int j = c0+e;
      float v = fin_(hInit[(size_t)(b0+row)*128 + j]);
      bf16 hi=(bf16)v, lo=(bf16)(v-(float)hi);
      h1H[row*136+j]=hi; h1L[row*136+j]=lo;
      h2H[row*136+j]=hi; h2L[row*136+j]=lo;
    }
  }
  for (int i=tid;i<16*40;i+=512){ pH[i]=(bf16)0.f; pL[i]=(bf16)0.f; }
  __syncthreads();

  // persistent gate accumulators (gh precomputed, gi appended)
  f32x4 c1R, c1Z, c1Nh, c2R, c2Z, c2Nh;

  auto ghpre = [&](){
    __builtin_amdgcn_s_setprio(1);
    c1R=Z4; c1Z=Z4; c1Nh=Z4; c2R=Z4; c2Z=Z4; c2Nh=Z4;
#pragma unroll
    for (int ks=0;ks<4;++ks){
      const int o = ks*32 + quad*8;
      bf16x8 aH = *(const bf16x8*)&h1H[lh*136 + o];
      bf16x8 aL = *(const bf16x8*)&h1L[lh*136 + o];
      c1R =MFMA(aH,a0RH[ks],c1R);  c1R =MFMA(aL,a0RH[ks],c1R);  c1R =MFMA(aH,a0RL[ks],c1R);
      c1Z =MFMA(aH,a0ZH[ks],c1Z);  c1Z =MFMA(aL,a0ZH[ks],c1Z);  c1Z =MFMA(aH,a0ZL[ks],c1Z);
      c1Nh=MFMA(aH,a0NH[ks],c1Nh); c1Nh=MFMA(aL,a0NH[ks],c1Nh); c1Nh=MFMA(aH,a0NL[ks],c1Nh);
    }
#pragma unroll
    for (int ks=0;ks<4;++ks){
      const int o = ks*32 + quad*8;
      bf16x8 aH = *(const bf16x8*)&h2H[lh*136 + o];
      bf16x8 aL = *(const bf16x8*)&h2L[lh*136 + o];
      c2R =MFMA(aH,a1RH[ks],c2R);  c2R =MFMA(aL,a1RH[ks],c2R);  c2R =MFMA(aH,a1RL[ks],c2R);
      c2Z =MFMA(aH,a1ZH[ks],c2Z);  c2Z =MFMA(aL,a1ZH[ks],c2Z);  c2Z =MFMA(aH,a1ZL[ks],c2Z);
      c2Nh=MFMA(aH,a1NH[ks],c2Nh); c2Nh=MFMA(aL,a1NH[ks],c2Nh); c2Nh=MFMA(aH,a1NL[ks],c2Nh);
    }
    __builtin_amdgcn_s_setprio(0);
  };
  ghpre();   // gh for t=0 (reads initial h1,h2; post-barrier)

  for (int t=0;t<512;++t){
    // ---- P1: gi1 (pred, K=32; W0i-hi from LDS, lo from L2) + gates1 + write h1(t). ----
    {
      f32x4 c1Ni = Z4;
      bf16x8 aP0 = *(const bf16x8*)&pH[lh*40 + quad*8];
      bf16x8 aP1 = *(const bf16x8*)&pL[lh*40 + quad*8];
      const int o = quad*8;
      bf16x8 bH,bL;
      bH=*(const bf16x8*)&w0iLds[cR*32 + (o^sw0)]; bL=*(const bf16x8*)(W0iL+(size_t)cR*32+o);
      c1R=MFMA(aP0,bH,c1R); c1R=MFMA(aP1,bH,c1R); c1R=MFMA(aP0,bL,c1R);
      bH=*(const bf16x8*)&w0iLds[cZ*32 + (o^sw0)]; bL=*(const bf16x8*)(W0iL+(size_t)cZ*32+o);
      c1Z=MFMA(aP0,bH,c1Z); c1Z=MFMA(aP1,bH,c1Z); c1Z=MFMA(aP0,bL,c1Z);
      bH=*(const bf16x8*)&w0iLds[cN*32 + (o^sw0)]; bL=*(const bf16x8*)(W0iL+(size_t)cN*32+o);
      c1Ni=MFMA(aP0,bH,c1Ni); c1Ni=MFMA(aP1,bH,c1Ni); c1Ni=MFMA(aP0,bL,c1Ni);
#pragma unroll
      for (int r=0;r<4;++r){
        const int m = quad*4+r;
        float rr = sigm_(c1R[r] + b1R);
        float z  = sigm_(c1Z[r] + b1Z);
        float nn = tanh_(c1Ni[r] + b1Ni + rr*(c1Nh[r] + b1Nh));
        float hold = (float)h1H[m*136+jc] + (float)h1L[m*136+jc];
        float hnew = fin_((1.f-z)*nn + z*hold);
        bf16 hi=(bf16)hnew;
        h1H[m*136+jc]=hi; h1L[m*136+jc]=(bf16)(hnew-(float)hi);
      }
    }
    LGKM_BAR();                            // B1: h1(t) visible (LDS drain only)
    // ---- P2: gi2 (h1(t), K=128; W1i-hi from LDS, lo from L2) + gates2 + write h2(t) ----
    {
      f32x4 c2Ni = Z4;
      __builtin_amdgcn_s_setprio(1);
#pragma unroll
      for (int ks=0;ks<4;++ks){
        const int o = ks*32 + quad*8;
        bf16x8 aH = *(const bf16x8*)&h1H[lh*136 + o];
        bf16x8 aL = *(const bf16x8*)&h1L[lh*136 + o];
        bf16x8 bH,bL;
        bH=*(const bf16x8*)&w1iLds[cR*128+(o^sw1)]; bL=*(const bf16x8*)(W1iL+(size_t)cR*128+o);
        c2R=MFMA(aH,bH,c2R); c2R=MFMA(aL,bH,c2R); c2R=MFMA(aH,bL,c2R);
        bH=*(const bf16x8*)&w1iLds[cZ*128+(o^sw1)]; bL=*(const bf16x8*)(W1iL+(size_t)cZ*128+o);
        c2Z=MFMA(aH,bH,c2Z); c2Z=MFMA(aL,bH,c2Z); c2Z=MFMA(aH,bL,c2Z);
        bH=*(const bf16x8*)&w1iLds[cN*128+(o^sw1)]; bL=*(const bf16x8*)(W1iL+(size_t)cN*128+o);
        c2Ni=MFMA(aH,bH,c2Ni); c2Ni=MFMA(aL,bH,c2Ni); c2Ni=MFMA(aH,bL,c2Ni);
      }
      __builtin_amdgcn_s_setprio(0);
#pragma unroll
      for (int r=0;r<4;++r){
        const int m = quad*4+r;
        float rr = sigm_(c2R[r] + b2R);
        float z  = sigm_(c2Z[r] + b2Z);
        float nn = tanh_(c2Ni[r] + b2Ni + rr*(c2Nh[r] + b2Nh));
        float hold = (float)h2H[m*136+jc] + (float)h2L[m*136+jc];
        float hnew = fin_((1.f-z)*nn + z*hold);
        bf16 hi=(bf16)hnew;
        h2H[m*136+jc]=hi; h2L[m*136+jc]=(bf16)(hnew-(float)hi);
      }
    }
    LGKM_BAR();                            // B2: h2(t) visible (LDS drain only)
    // ---- P3: out-proj (waves 0,1; Wo from LDS) + gh precompute for t+1 (all waves) ----
    if (wave<2){
      f32x4 po=Z4;
#pragma unroll
      for (int ks=0;ks<4;++ks){
        const int o = ks*32 + quad*8;
        bf16x8 oH = *(const bf16x8*)&h2H[lh*136 + o];
        bf16x8 oL = *(const bf16x8*)&h2L[lh*136 + o];
        const int wc = (wave*16+lh)*128 + (o^swo);
        bf16x8 bH = *(const bf16x8*)&woHl[wc];
        bf16x8 bL = *(const bf16x8*)&woLl[wc];
        po=MFMA(oH,bH,po); po=MFMA(oL,bH,po); po=MFMA(oH,bL,po);
      }
#pragma unroll
      for (int r=0;r<4;++r){
        const int m = quad*4+r;
        float pv = fin_(po[r]+bo);
        rec[((size_t)(b0+m)*512 + t)*32 + wave*16+lh] = pv;   // store floats across barrier
        bf16 hi=(bf16)pv;
        pH[m*40 + wave*16+lh]=hi; pL[m*40 + wave*16+lh]=(bf16)(pv-(float)hi);
      }
    }
    if (t+1 < 512) ghpre();                // reads h1(t),h2(t) — post-B2
    LGKM_BAR();                            // B3: pred(t) LDS visible; h reads done
  }
}

// ---------------------------------------------------------------------------
extern "C" void kernel_launch(void* const* d_in, const int* in_sizes, int n_in,
                              void* d_out, int out_size, void* d_ws, size_t ws_size,
                              hipStream_t stream)
{
  const float* x       = (const float*)d_in[0];
  const int*   lengths = (const int*)d_in[1];
  const float* eps     = (const float*)d_in[2];
  const float* eWih0   = (const float*)d_in[3];
  const float* eWhh0   = (const float*)d_in[4];
  const float* ebih0   = (const float*)d_in[5];
  const float* ebhh0   = (const float*)d_in[6];
  const float* eWih12  = (const float*)d_in[7];
  const float* eWhh12  = (const float*)d_in[8];
  const float* ebih12  = (const float*)d_in[9];
  const float* ebhh12  = (const float*)d_in[10];
  const float* dWih0   = (const float*)d_in[11];
  const float* dWhh0   = (const float*)d_in[12];
  const float* dbih0   = (const float*)d_in[13];
  const float* dbhh0   = (const float*)d_in[14];
  const float* dWih1   = (const float*)d_in[15];
  const float* dWhh1   = (const float*)d_in[16];
  const float* dbih1   = (const float*)d_in[17];
  const float* dbhh1   = (const float*)d_in[18];
  const float* Wm      = (const float*)d_in[19];
  const float* bm      = (const float*)d_in[20];
  const float* Wl      = (const float*)d_in[21];
  const float* bl      = (const float*)d_in[22];
  const float* Wz      = (const float*)d_in[23];
  const float* bz      = (const float*)d_in[24];
  const float* Wo      = (const float*)d_in[25];
  const float* bo      = (const float*)d_in[26];

  char* ws = (char*)d_ws;
  bf16* P     = (bf16*)ws;
  bf16* seqA  = (bf16*)(ws + (size_t)(4<<20));
  bf16* seqB  = (bf16*)(ws + (size_t)(68<<20));
  float* hF    = (float*)seqA;
  float* hB    = hF + 256*128;
  float* hInit = hB + 256*128;

  const size_t O_eWih0  = 0;
  const size_t O_eWhh0  = 49152;
  const size_t O_eWih12 = 245760;
  const size_t O_eWhh12 = 1032192;
  const size_t O_dWih0  = 1425408;
  const size_t O_dWhh0  = 1449984;
  const size_t O_dWih1  = 1548288;
  const size_t O_dWhh1  = 1646592;
  const size_t O_Wout   = 1744896;

  float* out   = (float*)d_out;
  float* rec   = out;
  float* omean = out + (size_t)4194304;
  float* ologv = omean + 8192;

  // No workspace memset — kernel output is independent of initial ws contents
  // (unwritten seq positions are never read at consumed indices; all other
  // regions are fully written before first read).

  PrepJobs J;
  const float* srcs[9] = {eWih0, eWhh0, eWih12, eWhh12, dWih0, dWhh0, dWih1, dWhh1, Wo};
  const size_t offs[9] = {O_eWih0,O_eWhh0,O_eWih12,O_eWhh12,O_dWih0,O_dWhh0,O_dWih1,O_dWhh1,O_Wout};
  const int    ns[9]   = {24576, 98304, 393216, 196608, 12288, 49152, 49152, 49152, 4096};
  for (int j=0;j<9;++j){ J.src[j]=srcs[j]; J.hi[j]=P+offs[j]; J.lo[j]=P+offs[j]+ns[j]; J.n[j]=ns[j]; }
  prep_w<<<256, 256, 0, stream>>>(J);

  dim3 blk(512);

  enc_rec<32,true><<<32, blk, 0, stream>>>(x, seqA,
      P+O_eWih0, P+O_eWih0+24576, P+O_eWhh0, P+O_eWhh0+98304,
      ebih0, ebhh0, lengths, nullptr, nullptr);
  enc_rec<256,false><<<32, blk, 0, stream>>>(seqA, seqB,
      P+O_eWih12, P+O_eWih12+393216, P+O_eWhh12, P+O_eWhh12+196608,
      ebih12, ebhh12, lengths, nullptr, nullptr);
  enc_rec<256,false><<<32, blk, 0, stream>>>(seqB, nullptr,
      P+O_eWih12+196608, P+O_eWih12+393216+196608,
      P+O_eWhh12+98304,  P+O_eWhh12+196608+98304,
      ebih12+768, ebhh12+768, lengths, hF, hB);
  latent_k<<<256, 64, 0, stream>>>(hF, hB, eps, Wm, bm, Wl, bl, Wz, bz,
                                   omean, ologv, hInit);
  dec_rec<<<16, blk, 0, stream>>>(hInit,
      P+O_dWih0, P+O_dWih0+12288, P+O_dWhh0, P+O_dWhh0+49152,
      P+O_dWih1, P+O_dWih1+49152, P+O_dWhh1, P+O_dWhh1+49152,
      P+O_Wout,  P+O_Wout+4096,
      dbih0, dbhh0, dbih1, dbhh1, bo, rec);
}